// Round 5
// baseline (118.043 us; speedup 1.0000x reference)
//
#include <hip/hip_runtime.h>
#include <hip/hip_bf16.h>

// Problem constants (B=8, S=4096, D=128 per reference setup_inputs)
#define B_ 8
#define S_ 4096
#define D_ 128

typedef __attribute__((ext_vector_type(8))) short bf16x8;   // MFMA A/B frag (4 VGPRs)
typedef __attribute__((ext_vector_type(4))) float f32x4;    // MFMA C/D frag
typedef __attribute__((ext_vector_type(4))) unsigned u32x4;

// f32 -> bf16 round-to-nearest-even
static __device__ __forceinline__ unsigned short f2bf(float x) {
    unsigned u = __float_as_uint(x);
    u += 0x7fffu + ((u >> 16) & 1u);
    return (unsigned short)(u >> 16);
}

// async global -> LDS, 16 bytes per lane (dest = wave-uniform base + lane*16)
typedef const __attribute__((address_space(1))) unsigned int* gas_ptr;
typedef __attribute__((address_space(3))) unsigned int* las_ptr;
static __device__ __forceinline__ void load_lds16(const unsigned short* g, unsigned short* l) {
    __builtin_amdgcn_global_load_lds((gas_ptr)(const void*)g, (las_ptr)(void*)l, 16, 0, 0);
}

#define WAIT_VMCNT_4 do { asm volatile("s_waitcnt vmcnt(4)" ::: "memory"); \
                          __builtin_amdgcn_sched_barrier(0); } while (0)
#define WAIT_VMCNT_0 do { asm volatile("s_waitcnt vmcnt(0)" ::: "memory"); \
                          __builtin_amdgcn_sched_barrier(0); } while (0)
#define BARRIER      do { __builtin_amdgcn_s_barrier(); \
                          __builtin_amdgcn_sched_barrier(0); } while (0)

// ---------------------------------------------------------------------------
// Fused prep: [0,2048) RoPE Q,K -> bf16 ; [2048,6144) zero d_out ;
//             [6144,6656) V transpose -> bf16
// ---------------------------------------------------------------------------
__global__ __launch_bounds__(256) void prep(const float* __restrict__ Q,
                                            const float* __restrict__ K,
                                            const float* __restrict__ V,
                                            unsigned short* __restrict__ Qr,
                                            unsigned short* __restrict__ Kr,
                                            unsigned short* __restrict__ Vt,
                                            float4* __restrict__ Oz) {
    __shared__ unsigned short tile[64][130];
    const int bid = blockIdx.x;
    if (bid < 2048) {
        int e = bid * 256 + threadIdx.x;          // 0 .. 8*4096*16-1
        int t = e & 15;
        int s = (e >> 4) & (S_ - 1);
        int b = e >> 16;
        size_t base = ((size_t)(b * S_ + s)) * D_;
        int d0 = t * 4;
        float qa[4], qb[4], ka[4], kb[4];
        *(float4*)qa = *(const float4*)(Q + base + d0);
        *(float4*)qb = *(const float4*)(Q + base + d0 + 64);
        *(float4*)ka = *(const float4*)(K + base + d0);
        *(float4*)kb = *(const float4*)(K + base + d0 + 64);
        unsigned short ql[4], qh[4], kl[4], kh[4];
        #pragma unroll
        for (int j = 0; j < 4; ++j) {
            float invf = exp2f(-0.20762050f * (float)(d0 + j));   // 10000^{-(d0+j)/64}
            float ang = (float)s * invf;
            float sn, cs;
            __sincosf(ang, &sn, &cs);
            ql[j] = f2bf(qa[j] * cs - qb[j] * sn);
            qh[j] = f2bf(qb[j] * cs + qa[j] * sn);
            kl[j] = f2bf(ka[j] * cs - kb[j] * sn);
            kh[j] = f2bf(kb[j] * cs + ka[j] * sn);
        }
        *reinterpret_cast<ushort4*>(Qr + base + d0)      = ushort4{ql[0], ql[1], ql[2], ql[3]};
        *reinterpret_cast<ushort4*>(Qr + base + d0 + 64) = ushort4{qh[0], qh[1], qh[2], qh[3]};
        *reinterpret_cast<ushort4*>(Kr + base + d0)      = ushort4{kl[0], kl[1], kl[2], kl[3]};
        *reinterpret_cast<ushort4*>(Kr + base + d0 + 64) = ushort4{kh[0], kh[1], kh[2], kh[3]};
    } else if (bid < 6144) {
        Oz[(size_t)(bid - 2048) * 256 + threadIdx.x] = float4{0.f, 0.f, 0.f, 0.f};
    } else {
        int b2 = bid - 6144;                      // 0..511
        int b  = b2 >> 6;
        int t0 = (b2 & 63) * 64;
        int tid = threadIdx.x;
        #pragma unroll
        for (int it = 0; it < 32; ++it) {
            int e = it * 256 + tid;
            int tl = e >> 7, d = e & 127;
            tile[tl][d] = f2bf(V[((size_t)(b * S_ + t0 + tl)) * D_ + d]);
        }
        __syncthreads();
        #pragma unroll
        for (int it = 0; it < 32; ++it) {
            int e = it * 256 + tid;
            int d = e >> 6, tl = e & 63;
            Vt[((size_t)(b * D_ + d)) * S_ + t0 + tl] = tile[tl][d];
        }
    }
}

// ---------------------------------------------------------------------------
// Causal no-softmax attention; stream-K balanced; counted-vmcnt pipeline.
//   768 blocks = 8 batches x 96 chunks of exactly 11 work items.
//   Work item w in [0,1056): q-tile qi owns [qi*(qi+1),(qi+1)*(qi+2)),
//   kt = w - qi*(qi+1) in [0, 2qi+2). BM=128 (4 waves x 32 rows), BN=64.
//   LDS 48KB: K double-buffered (DMA at iter top), V single-buffered
//   (DMA at iter bottom, consumed by next iter's PV). Raw s_barrier +
//   counted s_waitcnt vmcnt(N): DMAs stay in flight across barriers.
//   Per-iter: issue K(w+1) | QK^T | transpose | vmcnt(4)+bar (V(w) ready) |
//             PV | vmcnt(0)+bar (K(w+1) ready, Vb free) | issue V(w+1).
// MFMA 16x16x32 bf16 layouts (verified rounds 1-4):
//   A: lane l holds A[row=l&15][k=8*(l>>4)+j]; B: B[k=8*(l>>4)+j][col=l&15]
//   C/D: lane,reg holds D[row=4*(l>>4)+reg][col=l&15]
// ---------------------------------------------------------------------------
__global__ __launch_bounds__(256, 3) void attn(const unsigned short* __restrict__ Qr,
                                               const unsigned short* __restrict__ Kr,
                                               const unsigned short* __restrict__ Vt,
                                               float* __restrict__ Out) {
    __shared__ unsigned short Kb[2][64 * 128];   // [t][d] swizzled chunks, 2x16KB
    __shared__ unsigned short Vb[128 * 64];      // [d][t] swizzled chunks, 16KB

    const int r  = blockIdx.x;
    const int b  = r & 7;
    const int j  = r >> 3;                        // chunk 0..95
    const int w0 = j * 11;                        // exactly 11 items per chunk
    const int w1 = w0 + 11;

    int qi = 0;
    while ((qi + 1) * (qi + 2) <= w0) ++qi;
    int kt = w0 - qi * (qi + 1);

    const int tid = threadIdx.x;
    const int wv = tid >> 6;
    const int l  = tid & 63;
    const int g  = l >> 4;
    const int n  = l & 15;

    bf16x8 qf[2][4];
    auto hoistQ = [&](int qq) {
        #pragma unroll
        for (int rg = 0; rg < 2; ++rg) {
            const unsigned short* qp =
                Qr + ((size_t)(b * S_ + qq * 128 + wv * 32 + rg * 16 + n)) * D_ + 8 * g;
            #pragma unroll
            for (int ks = 0; ks < 4; ++ks)
                qf[rg][ks] = *reinterpret_cast<const bf16x8*>(qp + ks * 32);
        }
    };

    f32x4 o[2][8];
    auto zeroO = [&]() {
        #pragma unroll
        for (int rg = 0; rg < 2; ++rg)
            #pragma unroll
            for (int df = 0; df < 8; ++df) o[rg][df] = f32x4{0.f, 0.f, 0.f, 0.f};
    };
    auto flush = [&](int qq) {
        #pragma unroll
        for (int rg = 0; rg < 2; ++rg)
            #pragma unroll
            for (int df = 0; df < 8; ++df)
                #pragma unroll
                for (int rr = 0; rr < 4; ++rr) {
                    int srow = qq * 128 + wv * 32 + rg * 16 + 4 * g + rr;
                    atomicAdd(&Out[((size_t)(b * S_ + srow)) * D_ + df * 16 + n],
                              o[rg][df][rr]);
                }
    };

    // K LDS chunk (t,c) holds global chunk (t, c^(t&15)); V chunk (d,c): c^(d&7)
    auto stageK = [&](int bufk, int ktg) {
        const unsigned short* kbase = Kr + ((size_t)(b * S_ + ktg * 64)) * D_;
        #pragma unroll
        for (int i = 0; i < 4; ++i) {
            int ci = i * 256 + tid;
            int t = ci >> 4, c = ci & 15;
            load_lds16(kbase + t * D_ + ((c ^ (t & 15)) * 8), &Kb[bufk][ci * 8]);
        }
    };
    auto stageV = [&](int ktg) {
        const unsigned short* vbase = Vt + (size_t)b * D_ * S_ + ktg * 64;
        #pragma unroll
        for (int i = 0; i < 4; ++i) {
            int ci = i * 256 + tid;
            int d = ci >> 3, c = ci & 7;
            load_lds16(vbase + (size_t)d * S_ + ((c ^ (d & 7)) * 8), &Vb[ci * 8]);
        }
    };

    hoistQ(qi);
    zeroO();
    stageK(0, kt);                    // outstanding: K(w0) x4
    stageV(kt);                       // outstanding: K(w0) x4, V(w0) x4
    WAIT_VMCNT_4;                     // K(w0) done (V(w0) still in flight)
    BARRIER;

    int kb = 0;

    for (int w = w0; w < w1; ++w) {
        const int nkt = (kt + 1 == 2 * qi + 2) ? 0 : kt + 1;
        stageK(kb ^ 1, nkt);          // K(w+1); outstanding: V(w) x4, K(w+1) x4

        // ---- E^T = K.Q^T (swapped): lane(g,n) holds E[t=tf*16+4g+rr][s=rg*16+n]
        f32x4 e[2][4];
        #pragma unroll
        for (int rg = 0; rg < 2; ++rg)
            #pragma unroll
            for (int tf = 0; tf < 4; ++tf) e[rg][tf] = f32x4{0.f, 0.f, 0.f, 0.f};
        __builtin_amdgcn_s_setprio(1);
        #pragma unroll
        for (int tf = 0; tf < 4; ++tf) {
            #pragma unroll
            for (int ks = 0; ks < 4; ++ks) {
                const bf16x8 kf = *reinterpret_cast<const bf16x8*>(
                    &Kb[kb][(tf * 16 + n) * 128 + (((4 * ks + g) ^ n) * 8)]);
                e[0][tf] = __builtin_amdgcn_mfma_f32_16x16x32_bf16(kf, qf[0][ks], e[0][tf], 0, 0, 0);
                e[1][tf] = __builtin_amdgcn_mfma_f32_16x16x32_bf16(kf, qf[1][ks], e[1][tf], 0, 0, 0);
            }
        }
        __builtin_amdgcn_s_setprio(0);

        // ---- causal mask (diagonal-straddling tiles: kt in {2qi, 2qi+1})
        if (kt >= 2 * qi) {
            #pragma unroll
            for (int rg = 0; rg < 2; ++rg)
                #pragma unroll
                for (int tf = 0; tf < 4; ++tf) {
                    int s_glob = qi * 128 + wv * 32 + rg * 16 + n;
                    #pragma unroll
                    for (int rr = 0; rr < 4; ++rr) {
                        int t_glob = kt * 64 + tf * 16 + 4 * g + rr;
                        if (t_glob > s_glob) e[rg][tf][rr] = 0.f;
                    }
                }
        }

        // ---- E -> P A-frags fully in-register (cvt_pk + permlane swaps) ----
        bf16x8 pf[2][2];
        #pragma unroll
        for (int rg = 0; rg < 2; ++rg) {
            unsigned u0[4], u1[4];
            #pragma unroll
            for (int tf = 0; tf < 4; ++tf) {
                asm("v_cvt_pk_bf16_f32 %0, %1, %2"
                    : "=v"(u0[tf]) : "v"(e[rg][tf][0]), "v"(e[rg][tf][1]));
                asm("v_cvt_pk_bf16_f32 %0, %1, %2"
                    : "=v"(u1[tf]) : "v"(e[rg][tf][2]), "v"(e[rg][tf][3]));
            }
            #pragma unroll
            for (int ks = 0; ks < 2; ++ks) {
                unsigned a0 = u0[2 * ks], a1 = u0[2 * ks + 1];
                unsigned b0 = u1[2 * ks], b1 = u1[2 * ks + 1];
                asm("v_permlane32_swap_b32 %0, %1" : "+v"(a0), "+v"(a1));
                asm("v_permlane32_swap_b32 %0, %1" : "+v"(b0), "+v"(b1));
                asm("v_permlane16_swap_b32 %0, %1" : "+v"(a0), "+v"(a1));
                asm("v_permlane16_swap_b32 %0, %1" : "+v"(b0), "+v"(b1));
                u32x4 wds = u32x4{a0, b0, a1, b1};
                pf[rg][ks] = __builtin_bit_cast(bf16x8, wds);
            }
        }

        WAIT_VMCNT_4;                 // V(w) done (mine); K(w+1) stays in flight
        BARRIER;                      // V(w) visible to all; all done reading Kb[kb^1]

        // ---- O += P.V ----
        __builtin_amdgcn_s_setprio(1);
        #pragma unroll
        for (int df = 0; df < 8; ++df) {
            #pragma unroll
            for (int ks = 0; ks < 2; ++ks) {
                const bf16x8 vf = *reinterpret_cast<const bf16x8*>(
                    &Vb[(df * 16 + n) * 64 + (((4 * ks + g) ^ (n & 7)) * 8)]);
                o[0][df] = __builtin_amdgcn_mfma_f32_16x16x32_bf16(pf[0][ks], vf, o[0][df], 0, 0, 0);
                o[1][df] = __builtin_amdgcn_mfma_f32_16x16x32_bf16(pf[1][ks], vf, o[1][df], 0, 0, 0);
            }
        }
        __builtin_amdgcn_s_setprio(0);

        WAIT_VMCNT_0;                 // K(w+1) done (had QK^T+PV to land)
        BARRIER;                      // all waves: PV done (Vb free) + K(w+1) ready
        stageV(nkt);                  // V(w+1) into Vb; stays in flight into next iter

        kb ^= 1;
        ++kt;
        if (kt == 2 * qi + 2 && w + 1 < w1) {     // q-tile crossing mid-chunk
            flush(qi);
            zeroO();
            ++qi;
            kt = 0;
            hoistQ(qi);               // extra vmcnt entries; later waits over-wait (safe)
        }
    }
    WAIT_VMCNT_0;                     // drain dummy tail DMAs before exit
    flush(qi);
}

// ---------------------------------------------------------------------------
extern "C" void kernel_launch(void* const* d_in, const int* in_sizes, int n_in,
                              void* d_out, int out_size, void* d_ws, size_t ws_size,
                              hipStream_t stream) {
    const float* Q = (const float*)d_in[0];
    const float* K = (const float*)d_in[1];
    const float* V = (const float*)d_in[2];

    unsigned short* Qr = (unsigned short*)d_ws;
    unsigned short* Kr = Qr + (size_t)B_ * S_ * D_;
    unsigned short* Vt = Kr + (size_t)B_ * S_ * D_;

    prep<<<6656, 256, 0, stream>>>(Q, K, V, Qr, Kr, Vt, (float4*)d_out);
    attn<<<768, 256, 0, stream>>>(Qr, Kr, Vt, (float*)d_out);
}

// Round 6
// 77.845 us; speedup vs baseline: 1.5164x; 1.5164x over previous
//
#include <hip/hip_runtime.h>
#include <hip/hip_bf16.h>

// Problem constants (B=8, S=4096, D=128 per reference setup_inputs)
#define B_ 8
#define S_ 4096
#define D_ 128

typedef __attribute__((ext_vector_type(8))) short bf16x8;   // MFMA A/B frag (4 VGPRs)
typedef __attribute__((ext_vector_type(4))) float f32x4;    // MFMA C/D frag
typedef __attribute__((ext_vector_type(4))) unsigned u32x4;

// f32 -> bf16 round-to-nearest-even
static __device__ __forceinline__ unsigned short f2bf(float x) {
    unsigned u = __float_as_uint(x);
    u += 0x7fffu + ((u >> 16) & 1u);
    return (unsigned short)(u >> 16);
}

// async global -> LDS, 16 bytes per lane (dest = wave-uniform base + lane*16)
typedef const __attribute__((address_space(1))) unsigned int* gas_ptr;
typedef __attribute__((address_space(3))) unsigned int* las_ptr;
static __device__ __forceinline__ void load_lds16(const unsigned short* g, unsigned short* l) {
    __builtin_amdgcn_global_load_lds((gas_ptr)(const void*)g, (las_ptr)(void*)l, 16, 0, 0);
}

#define WAIT_VMCNT_8 do { asm volatile("s_waitcnt vmcnt(8)" ::: "memory"); \
                          __builtin_amdgcn_sched_barrier(0); } while (0)
#define WAIT_VMCNT_0 do { asm volatile("s_waitcnt vmcnt(0)" ::: "memory"); \
                          __builtin_amdgcn_sched_barrier(0); } while (0)
#define BARRIER      do { __builtin_amdgcn_s_barrier(); \
                          __builtin_amdgcn_sched_barrier(0); } while (0)

// ---------------------------------------------------------------------------
// Fused prep: [0,2048) RoPE Q,K -> bf16 ; [2048,6144) zero d_out ;
//             [6144,6656) V transpose -> bf16
// ---------------------------------------------------------------------------
__global__ __launch_bounds__(256) void prep(const float* __restrict__ Q,
                                            const float* __restrict__ K,
                                            const float* __restrict__ V,
                                            unsigned short* __restrict__ Qr,
                                            unsigned short* __restrict__ Kr,
                                            unsigned short* __restrict__ Vt,
                                            float4* __restrict__ Oz) {
    __shared__ unsigned short tile[64][130];
    const int bid = blockIdx.x;
    if (bid < 2048) {
        int e = bid * 256 + threadIdx.x;          // 0 .. 8*4096*16-1
        int t = e & 15;
        int s = (e >> 4) & (S_ - 1);
        int b = e >> 16;
        size_t base = ((size_t)(b * S_ + s)) * D_;
        int d0 = t * 4;
        float qa[4], qb[4], ka[4], kb[4];
        *(float4*)qa = *(const float4*)(Q + base + d0);
        *(float4*)qb = *(const float4*)(Q + base + d0 + 64);
        *(float4*)ka = *(const float4*)(K + base + d0);
        *(float4*)kb = *(const float4*)(K + base + d0 + 64);
        unsigned short ql[4], qh[4], kl[4], kh[4];
        #pragma unroll
        for (int j = 0; j < 4; ++j) {
            float invf = exp2f(-0.20762050f * (float)(d0 + j));   // 10000^{-(d0+j)/64}
            float ang = (float)s * invf;
            float sn, cs;
            __sincosf(ang, &sn, &cs);
            ql[j] = f2bf(qa[j] * cs - qb[j] * sn);
            qh[j] = f2bf(qb[j] * cs + qa[j] * sn);
            kl[j] = f2bf(ka[j] * cs - kb[j] * sn);
            kh[j] = f2bf(kb[j] * cs + ka[j] * sn);
        }
        *reinterpret_cast<ushort4*>(Qr + base + d0)      = ushort4{ql[0], ql[1], ql[2], ql[3]};
        *reinterpret_cast<ushort4*>(Qr + base + d0 + 64) = ushort4{qh[0], qh[1], qh[2], qh[3]};
        *reinterpret_cast<ushort4*>(Kr + base + d0)      = ushort4{kl[0], kl[1], kl[2], kl[3]};
        *reinterpret_cast<ushort4*>(Kr + base + d0 + 64) = ushort4{kh[0], kh[1], kh[2], kh[3]};
    } else if (bid < 6144) {
        Oz[(size_t)(bid - 2048) * 256 + threadIdx.x] = float4{0.f, 0.f, 0.f, 0.f};
    } else {
        int b2 = bid - 6144;                      // 0..511
        int b  = b2 >> 6;
        int t0 = (b2 & 63) * 64;
        int tid = threadIdx.x;
        #pragma unroll
        for (int it = 0; it < 32; ++it) {
            int e = it * 256 + tid;
            int tl = e >> 7, d = e & 127;
            tile[tl][d] = f2bf(V[((size_t)(b * S_ + t0 + tl)) * D_ + d]);
        }
        __syncthreads();
        #pragma unroll
        for (int it = 0; it < 32; ++it) {
            int e = it * 256 + tid;
            int d = e >> 6, tl = e & 63;
            Vt[((size_t)(b * D_ + d)) * S_ + t0 + tl] = tile[tl][d];
        }
    }
}

// ---------------------------------------------------------------------------
// Causal no-softmax attention; stream-K balanced; 2-deep counted-vmcnt pipe.
//   512 blocks = 8 batches x 64 chunks of 16-17 work items (round-4 chunking).
//   Work item w in [0,1056): q-tile qi owns [qi*(qi+1),(qi+1)*(qi+2)),
//   kt = w - qi*(qi+1) in [0, 2qi+2). BM=128 (4 waves x 32 rows), BN=64.
//   K and V double-buffered (64KB LDS). Per iter:
//     vmcnt(8) [tile w landed; tile w+1 in flight] + barrier
//     QK^T | mask | in-reg transpose | PV        (all from buf = w&1)
//     barrier [buf free] | stage tile w+2 into buf (only if it exists)
//     [tile crossing: flush atomics issued AFTER stage -> youngest in vmcnt]
//   Last iter uses vmcnt(0). No dummy stages, no atomic in counted window
//   except rare crossings (over-wait, safe).
// MFMA 16x16x32 bf16 layouts (verified rounds 1-5):
//   A: lane l holds A[row=l&15][k=8*(l>>4)+j]; B: B[k=8*(l>>4)+j][col=l&15]
//   C/D: lane,reg holds D[row=4*(l>>4)+reg][col=l&15]
// ---------------------------------------------------------------------------
__global__ __launch_bounds__(256, 2) void attn(const unsigned short* __restrict__ Qr,
                                               const unsigned short* __restrict__ Kr,
                                               const unsigned short* __restrict__ Vt,
                                               float* __restrict__ Out) {
    __shared__ unsigned short Kb[2][64 * 128];   // [t][d] swizzled chunks, 2x16KB
    __shared__ unsigned short Vb[2][128 * 64];   // [d][t] swizzled chunks, 2x16KB

    const int r  = blockIdx.x;
    const int b  = r & 7;
    const int j  = r >> 3;                        // chunk 0..63 within batch
    const int w0 = (j * 33) >> 1;                 // [w0,w1): 16 or 17 items
    const int w1 = ((j + 1) * 33) >> 1;

    int qi = 0;
    while ((qi + 1) * (qi + 2) <= w0) ++qi;
    int kt = w0 - qi * (qi + 1);

    const int tid = threadIdx.x;
    const int wv = tid >> 6;
    const int l  = tid & 63;
    const int g  = l >> 4;
    const int n  = l & 15;

    bf16x8 qf[2][4];
    auto hoistQ = [&](int qq) {
        #pragma unroll
        for (int rg = 0; rg < 2; ++rg) {
            const unsigned short* qp =
                Qr + ((size_t)(b * S_ + qq * 128 + wv * 32 + rg * 16 + n)) * D_ + 8 * g;
            #pragma unroll
            for (int ks = 0; ks < 4; ++ks)
                qf[rg][ks] = *reinterpret_cast<const bf16x8*>(qp + ks * 32);
        }
    };

    f32x4 o[2][8];
    auto zeroO = [&]() {
        #pragma unroll
        for (int rg = 0; rg < 2; ++rg)
            #pragma unroll
            for (int df = 0; df < 8; ++df) o[rg][df] = f32x4{0.f, 0.f, 0.f, 0.f};
    };
    auto flush = [&](int qq) {
        #pragma unroll
        for (int rg = 0; rg < 2; ++rg)
            #pragma unroll
            for (int df = 0; df < 8; ++df)
                #pragma unroll
                for (int rr = 0; rr < 4; ++rr) {
                    int srow = qq * 128 + wv * 32 + rg * 16 + 4 * g + rr;
                    atomicAdd(&Out[((size_t)(b * S_ + srow)) * D_ + df * 16 + n],
                              o[rg][df][rr]);
                }
    };

    // K LDS chunk (t,c) holds global chunk (t, c^(t&15)); V chunk (d,c): c^(d&7)
    auto stage = [&](int bufs, int ktg) {
        const unsigned short* kbase = Kr + ((size_t)(b * S_ + ktg * 64)) * D_;
        #pragma unroll
        for (int i = 0; i < 4; ++i) {
            int ci = i * 256 + tid;
            int t = ci >> 4, c = ci & 15;
            load_lds16(kbase + t * D_ + ((c ^ (t & 15)) * 8), &Kb[bufs][ci * 8]);
        }
        const unsigned short* vbase = Vt + (size_t)b * D_ * S_ + ktg * 64;
        #pragma unroll
        for (int i = 0; i < 4; ++i) {
            int ci = i * 256 + tid;
            int d = ci >> 3, c = ci & 7;
            load_lds16(vbase + (size_t)d * S_ + ((c ^ (d & 7)) * 8), &Vb[bufs][ci * 8]);
        }
    };

    hoistQ(qi);
    zeroO();
    stage(0, kt);                                  // tile w0       (8 entries/wave)
    {
        int k1 = kt + 1;
        if (k1 >= 2 * qi + 2) k1 = 0;              // tile w0+1 may start next q-tile
        stage(1, k1);                              // tile w0+1     (8 more)
    }

    int buf = 0;

    for (int w = w0; w < w1; ++w) {
        if (w == w1 - 1) { WAIT_VMCNT_0; }         // final tile: nothing behind it
        else             { WAIT_VMCNT_8; }         // tile w landed; w+1 in flight
        BARRIER;                                   // all waves' DMA writes visible

        // ---- E^T = K.Q^T (swapped): lane(g,n) holds E[t=tf*16+4g+rr][s=rg*16+n]
        f32x4 e[2][4];
        #pragma unroll
        for (int rg = 0; rg < 2; ++rg)
            #pragma unroll
            for (int tf = 0; tf < 4; ++tf) e[rg][tf] = f32x4{0.f, 0.f, 0.f, 0.f};
        __builtin_amdgcn_s_setprio(1);
        #pragma unroll
        for (int tf = 0; tf < 4; ++tf) {
            #pragma unroll
            for (int ks = 0; ks < 4; ++ks) {
                const bf16x8 kf = *reinterpret_cast<const bf16x8*>(
                    &Kb[buf][(tf * 16 + n) * 128 + (((4 * ks + g) ^ n) * 8)]);
                e[0][tf] = __builtin_amdgcn_mfma_f32_16x16x32_bf16(kf, qf[0][ks], e[0][tf], 0, 0, 0);
                e[1][tf] = __builtin_amdgcn_mfma_f32_16x16x32_bf16(kf, qf[1][ks], e[1][tf], 0, 0, 0);
            }
        }
        __builtin_amdgcn_s_setprio(0);

        // ---- causal mask (diagonal-straddling tiles: kt in {2qi, 2qi+1})
        if (kt >= 2 * qi) {
            #pragma unroll
            for (int rg = 0; rg < 2; ++rg)
                #pragma unroll
                for (int tf = 0; tf < 4; ++tf) {
                    int s_glob = qi * 128 + wv * 32 + rg * 16 + n;
                    #pragma unroll
                    for (int rr = 0; rr < 4; ++rr) {
                        int t_glob = kt * 64 + tf * 16 + 4 * g + rr;
                        if (t_glob > s_glob) e[rg][tf][rr] = 0.f;
                    }
                }
        }

        // ---- E -> P A-frags fully in-register (cvt_pk + permlane swaps) ----
        bf16x8 pf[2][2];
        #pragma unroll
        for (int rg = 0; rg < 2; ++rg) {
            unsigned u0[4], u1[4];
            #pragma unroll
            for (int tf = 0; tf < 4; ++tf) {
                asm("v_cvt_pk_bf16_f32 %0, %1, %2"
                    : "=v"(u0[tf]) : "v"(e[rg][tf][0]), "v"(e[rg][tf][1]));
                asm("v_cvt_pk_bf16_f32 %0, %1, %2"
                    : "=v"(u1[tf]) : "v"(e[rg][tf][2]), "v"(e[rg][tf][3]));
            }
            #pragma unroll
            for (int ks = 0; ks < 2; ++ks) {
                unsigned a0 = u0[2 * ks], a1 = u0[2 * ks + 1];
                unsigned b0 = u1[2 * ks], b1 = u1[2 * ks + 1];
                asm("v_permlane32_swap_b32 %0, %1" : "+v"(a0), "+v"(a1));
                asm("v_permlane32_swap_b32 %0, %1" : "+v"(b0), "+v"(b1));
                asm("v_permlane16_swap_b32 %0, %1" : "+v"(a0), "+v"(a1));
                asm("v_permlane16_swap_b32 %0, %1" : "+v"(b0), "+v"(b1));
                u32x4 wds = u32x4{a0, b0, a1, b1};
                pf[rg][ks] = __builtin_bit_cast(bf16x8, wds);
            }
        }

        // ---- O += P.V ----
        __builtin_amdgcn_s_setprio(1);
        #pragma unroll
        for (int df = 0; df < 8; ++df) {
            #pragma unroll
            for (int ks = 0; ks < 2; ++ks) {
                const bf16x8 vf = *reinterpret_cast<const bf16x8*>(
                    &Vb[buf][(df * 16 + n) * 64 + (((4 * ks + g) ^ (n & 7)) * 8)]);
                o[0][df] = __builtin_amdgcn_mfma_f32_16x16x32_bf16(pf[0][ks], vf, o[0][df], 0, 0, 0);
                o[1][df] = __builtin_amdgcn_mfma_f32_16x16x32_bf16(pf[1][ks], vf, o[1][df], 0, 0, 0);
            }
        }
        __builtin_amdgcn_s_setprio(0);

        BARRIER;                                   // all waves done reading buf

        if (w + 2 < w1) {                          // stage tile w+2 into freed buf
            int k2 = kt + 2;
            const int lim = 2 * qi + 2;
            if (k2 >= lim) k2 -= lim;              // next q-tile's kt (K addr = kt only)
            stage(buf, k2);
        }

        buf ^= 1;
        ++kt;
        if (kt == 2 * qi + 2 && w + 1 < w1) {      // q-tile crossing mid-chunk
            flush(qi);                             // atomics AFTER stage -> youngest
            zeroO();
            ++qi;
            kt = 0;
            hoistQ(qi);                            // rare over-wait next iter; safe
        }
    }
    flush(qi);
}

// ---------------------------------------------------------------------------
extern "C" void kernel_launch(void* const* d_in, const int* in_sizes, int n_in,
                              void* d_out, int out_size, void* d_ws, size_t ws_size,
                              hipStream_t stream) {
    const float* Q = (const float*)d_in[0];
    const float* K = (const float*)d_in[1];
    const float* V = (const float*)d_in[2];

    unsigned short* Qr = (unsigned short*)d_ws;
    unsigned short* Kr = Qr + (size_t)B_ * S_ * D_;
    unsigned short* Vt = Kr + (size_t)B_ * S_ * D_;

    prep<<<6656, 256, 0, stream>>>(Q, K, V, Qr, Kr, Vt, (float4*)d_out);
    attn<<<512, 256, 0, stream>>>(Qr, Kr, Vt, (float*)d_out);
}